// Round 1
// baseline (1527.045 us; speedup 1.0000x reference)
//
#include <hip/hip_runtime.h>
#include <math.h>

#define TL 2048
#define TD 768
#define NH 12
#define HD 64
#define NB 4
#define MTOT (NB * TL)   // 8192

// ---------------------------------------------------------------------------
// Kernel 1: fused QKV projection.  C = x @ W + b, scattered to [B,H,L,hd].
// 64x64 output tile, BK=32, 256 threads, 4x4 micro-tile per thread.
// blockIdx.z selects which of Wq/Wk/Wv.
// ---------------------------------------------------------------------------
__global__ __launch_bounds__(256)
void qkv_kernel(const float* __restrict__ x,
                const float* __restrict__ Wq, const float* __restrict__ bq,
                const float* __restrict__ Wk, const float* __restrict__ bk,
                const float* __restrict__ Wv, const float* __restrict__ bv,
                float* __restrict__ Qo, float* __restrict__ Ko, float* __restrict__ Vo)
{
    const int which = blockIdx.z;
    const float* W    = (which == 0) ? Wq : (which == 1 ? Wk : Wv);
    const float* bias = (which == 0) ? bq : (which == 1 ? bk : bv);
    float* out        = (which == 0) ? Qo : (which == 1 ? Ko : Vo);

    __shared__ float As[32][68];   // [k][m] (A transposed), pad for bank spread
    __shared__ float Bs[32][68];   // [k][n]

    const int t  = threadIdx.x;
    const int ty = t >> 4;         // 0..15 -> rows 4*ty..4*ty+3
    const int tx = t & 15;         // 0..15 -> cols 4*tx..4*tx+3
    const int m0 = blockIdx.x << 6;
    const int n0 = blockIdx.y << 6;

    const int ar  = t >> 3;        // 0..31  A row (stage 2 rows of 32)
    const int as_ = t & 7;         // 0..7   A k-seg (x4 floats)
    const int bk_ = t >> 4;        // 0..15  B k row (stage 2)
    const int bs  = t & 15;        // 0..15  B n-seg (x4 floats)

    float acc[4][4] = {};

    for (int kk = 0; kk < TD; kk += 32) {
#pragma unroll
        for (int it = 0; it < 2; ++it) {
            int row = ar + (it << 5);
            float4 a4 = *(const float4*)(x + (size_t)(m0 + row) * TD + kk + (as_ << 2));
            As[(as_ << 2) + 0][row] = a4.x;
            As[(as_ << 2) + 1][row] = a4.y;
            As[(as_ << 2) + 2][row] = a4.z;
            As[(as_ << 2) + 3][row] = a4.w;
            int kr = bk_ + (it << 4);
            float4 b4 = *(const float4*)(W + (size_t)(kk + kr) * TD + n0 + (bs << 2));
            *(float4*)&Bs[kr][bs << 2] = b4;
        }
        __syncthreads();
#pragma unroll
        for (int k = 0; k < 32; ++k) {
            float4 a4 = *(const float4*)&As[k][ty << 2];
            float4 b4 = *(const float4*)&Bs[k][tx << 2];
            float a[4] = {a4.x, a4.y, a4.z, a4.w};
            float b[4] = {b4.x, b4.y, b4.z, b4.w};
#pragma unroll
            for (int i = 0; i < 4; ++i)
#pragma unroll
                for (int j = 0; j < 4; ++j)
                    acc[i][j] = fmaf(a[i], b[j], acc[i][j]);
        }
        __syncthreads();
    }

    // epilogue: BN == HD so this column-block is exactly head h = blockIdx.y
    const int h = blockIdx.y;
    float4 bb4 = *(const float4*)(bias + n0 + (tx << 2));
#pragma unroll
    for (int i = 0; i < 4; ++i) {
        int m  = m0 + (ty << 2) + i;
        int b_ = m >> 11;           // / 2048
        int l  = m & (TL - 1);
        float4 r;
        r.x = acc[i][0] + bb4.x;
        r.y = acc[i][1] + bb4.y;
        r.z = acc[i][2] + bb4.z;
        r.w = acc[i][3] + bb4.w;
        *(float4*)(out + (((size_t)(b_ * NH + h) * TL + l) << 6) + (tx << 2)) = r;
    }
}

// ---------------------------------------------------------------------------
// Kernel 2: flash-style attention, fp32.
// One block per (bh, 64-row Q tile). Streams K/V tiles of 64 with online
// softmax. St stored transposed [col][row]: conflict-free softmax scan and
// float4 P-fragment reads in the PV phase. K and V share one LDS buffer.
// ---------------------------------------------------------------------------
__global__ __launch_bounds__(256)
void attn_kernel(const float* __restrict__ Q, const float* __restrict__ K,
                 const float* __restrict__ V, float* __restrict__ O)
{
    __shared__ float Qt[64][68];    // [d][qrow], pre-scaled by 1/8
    __shared__ float KV[64][68];    // phase 1: Kt[d][kcol]; phase 2: Vs[j][d]
    __shared__ float St[64][68];    // [kcol][qrow] scores, then P=exp(..)
    __shared__ float rowM[64], rowL[64], rowA[64];

    const int t  = threadIdx.x;
    const int ty = t >> 4;          // 0..15 -> q rows 4*ty..+3
    const int tx = t & 15;          // 0..15 -> k cols / d cols 4*tx..+3
    const int q0 = blockIdx.x << 6;
    const int bh = blockIdx.y;
    const float* Qb = Q + ((size_t)bh << 17);   // bh * 2048 * 64
    const float* Kb = K + ((size_t)bh << 17);
    const float* Vb = V + ((size_t)bh << 17);

    const int lr = t >> 4;          // 0..15 (row base, +16 x4)
    const int ls = t & 15;          // d-seg

#pragma unroll
    for (int it = 0; it < 4; ++it) {
        int r = lr + (it << 4);
        float4 q4 = *(const float4*)(Qb + ((size_t)(q0 + r) << 6) + (ls << 2));
        Qt[(ls << 2) + 0][r] = q4.x * 0.125f;
        Qt[(ls << 2) + 1][r] = q4.y * 0.125f;
        Qt[(ls << 2) + 2][r] = q4.z * 0.125f;
        Qt[(ls << 2) + 3][r] = q4.w * 0.125f;
    }
    if (t < 64) { rowM[t] = -1e30f; rowL[t] = 0.0f; }

    float o[4][4] = {};

    for (int kt = 0; kt < TL / 64; ++kt) {
        const int k0 = kt << 6;
        __syncthreads();            // prev PV done with KV/St (and Qt/rowM at kt=0)
        // load K tile transposed
#pragma unroll
        for (int it = 0; it < 4; ++it) {
            int r = lr + (it << 4);
            float4 k4 = *(const float4*)(Kb + ((size_t)(k0 + r) << 6) + (ls << 2));
            KV[(ls << 2) + 0][r] = k4.x;
            KV[(ls << 2) + 1][r] = k4.y;
            KV[(ls << 2) + 2][r] = k4.z;
            KV[(ls << 2) + 3][r] = k4.w;
        }
        __syncthreads();
        // S = (Q/8) @ K^T, 4x4 per thread
        float s[4][4] = {};
#pragma unroll
        for (int d = 0; d < 64; ++d) {
            float4 a4 = *(const float4*)&Qt[d][ty << 2];
            float4 b4 = *(const float4*)&KV[d][tx << 2];
            float a[4] = {a4.x, a4.y, a4.z, a4.w};
            float b[4] = {b4.x, b4.y, b4.z, b4.w};
#pragma unroll
            for (int i = 0; i < 4; ++i)
#pragma unroll
                for (int j = 0; j < 4; ++j)
                    s[i][j] = fmaf(a[i], b[j], s[i][j]);
        }
        // store S transposed: St[col][row]
#pragma unroll
        for (int j = 0; j < 4; ++j) {
            float4 c;
            c.x = s[0][j]; c.y = s[1][j]; c.z = s[2][j]; c.w = s[3][j];
            *(float4*)&St[(tx << 2) + j][ty << 2] = c;
        }
        __syncthreads();            // St ready; K reads done -> reuse KV for V
        // load V tile (all threads) while wave 0 will do softmax
#pragma unroll
        for (int it = 0; it < 4; ++it) {
            int r = lr + (it << 4);
            float4 v4 = *(const float4*)(Vb + ((size_t)(k0 + r) << 6) + (ls << 2));
            *(float4*)&KV[r][ls << 2] = v4;
        }
        // online softmax: thread r owns q-row r, scans St[:][r] (conflict-free)
        if (t < 64) {
            float mx = -1e30f;
#pragma unroll 8
            for (int c = 0; c < 64; ++c) mx = fmaxf(mx, St[c][t]);
            float mOld = rowM[t];
            float mNew = fmaxf(mOld, mx);
            float alpha = __expf(mOld - mNew);
            float sum = 0.0f;
#pragma unroll 8
            for (int c = 0; c < 64; ++c) {
                float e = __expf(St[c][t] - mNew);
                St[c][t] = e;
                sum += e;
            }
            rowL[t] = rowL[t] * alpha + sum;
            rowM[t] = mNew;
            rowA[t] = alpha;
        }
        __syncthreads();
        // rescale O and accumulate P @ V
        float al[4];
#pragma unroll
        for (int i = 0; i < 4; ++i) al[i] = rowA[(ty << 2) + i];
#pragma unroll
        for (int i = 0; i < 4; ++i)
#pragma unroll
            for (int j = 0; j < 4; ++j) o[i][j] *= al[i];
#pragma unroll
        for (int j = 0; j < 64; ++j) {
            float4 p4 = *(const float4*)&St[j][ty << 2];   // P[4ty..+3][j]
            float4 v4 = *(const float4*)&KV[j][tx << 2];   // V[j][4tx..+3]
            float p[4] = {p4.x, p4.y, p4.z, p4.w};
            float v[4] = {v4.x, v4.y, v4.z, v4.w};
#pragma unroll
            for (int i = 0; i < 4; ++i)
#pragma unroll
                for (int c = 0; c < 4; ++c)
                    o[i][c] = fmaf(p[i], v[c], o[i][c]);
        }
    }

    // epilogue: normalize and write O in [B, L, D] layout
    const int bb = bh / NH, hh = bh % NH;
#pragma unroll
    for (int i = 0; i < 4; ++i) {
        float inv = 1.0f / rowL[(ty << 2) + i];
        float4 r;
        r.x = o[i][0] * inv;
        r.y = o[i][1] * inv;
        r.z = o[i][2] * inv;
        r.w = o[i][3] * inv;
        *(float4*)(O + (size_t)(bb * TL + q0 + (ty << 2) + i) * TD + hh * HD + (tx << 2)) = r;
    }
}

// ---------------------------------------------------------------------------
// Kernel 3: output projection.  out = O @ Wo + bo, plain [8192,768] GEMM.
// ---------------------------------------------------------------------------
__global__ __launch_bounds__(256)
void oproj_kernel(const float* __restrict__ A, const float* __restrict__ W,
                  const float* __restrict__ bias, float* __restrict__ C)
{
    __shared__ float As[32][68];
    __shared__ float Bs[32][68];

    const int t  = threadIdx.x;
    const int ty = t >> 4, tx = t & 15;
    const int m0 = blockIdx.x << 6;
    const int n0 = blockIdx.y << 6;

    const int ar  = t >> 3;
    const int as_ = t & 7;
    const int bk_ = t >> 4;
    const int bs  = t & 15;

    float acc[4][4] = {};

    for (int kk = 0; kk < TD; kk += 32) {
#pragma unroll
        for (int it = 0; it < 2; ++it) {
            int row = ar + (it << 5);
            float4 a4 = *(const float4*)(A + (size_t)(m0 + row) * TD + kk + (as_ << 2));
            As[(as_ << 2) + 0][row] = a4.x;
            As[(as_ << 2) + 1][row] = a4.y;
            As[(as_ << 2) + 2][row] = a4.z;
            As[(as_ << 2) + 3][row] = a4.w;
            int kr = bk_ + (it << 4);
            float4 b4 = *(const float4*)(W + (size_t)(kk + kr) * TD + n0 + (bs << 2));
            *(float4*)&Bs[kr][bs << 2] = b4;
        }
        __syncthreads();
#pragma unroll
        for (int k = 0; k < 32; ++k) {
            float4 a4 = *(const float4*)&As[k][ty << 2];
            float4 b4 = *(const float4*)&Bs[k][tx << 2];
            float a[4] = {a4.x, a4.y, a4.z, a4.w};
            float b[4] = {b4.x, b4.y, b4.z, b4.w};
#pragma unroll
            for (int i = 0; i < 4; ++i)
#pragma unroll
                for (int j = 0; j < 4; ++j)
                    acc[i][j] = fmaf(a[i], b[j], acc[i][j]);
        }
        __syncthreads();
    }

    float4 bb4 = *(const float4*)(bias + n0 + (tx << 2));
#pragma unroll
    for (int i = 0; i < 4; ++i) {
        int m = m0 + (ty << 2) + i;
        float4 r;
        r.x = acc[i][0] + bb4.x;
        r.y = acc[i][1] + bb4.y;
        r.z = acc[i][2] + bb4.z;
        r.w = acc[i][3] + bb4.w;
        *(float4*)(C + (size_t)m * TD + n0 + (tx << 2)) = r;
    }
}

// ---------------------------------------------------------------------------
extern "C" void kernel_launch(void* const* d_in, const int* in_sizes, int n_in,
                              void* d_out, int out_size, void* d_ws, size_t ws_size,
                              hipStream_t stream)
{
    const float* x  = (const float*)d_in[0];
    const float* Wq = (const float*)d_in[1];
    const float* bq = (const float*)d_in[2];
    const float* Wk = (const float*)d_in[3];
    const float* bk = (const float*)d_in[4];
    const float* Wv = (const float*)d_in[5];
    const float* bv = (const float*)d_in[6];
    const float* Wo = (const float*)d_in[7];
    const float* bo = (const float*)d_in[8];
    float* out = (float*)d_out;

    const size_t per = (size_t)NB * NH * TL * HD;   // 6,291,456 floats
    float* Q = (float*)d_ws;        // ws usage: 4 * 25.2 MB = 100.7 MB
    float* K = Q + per;
    float* V = K + per;
    float* O = V + per;             // attention output in [B, L, D]

    qkv_kernel<<<dim3(MTOT / 64, TD / 64, 3), 256, 0, stream>>>(
        x, Wq, bq, Wk, bk, Wv, bv, Q, K, V);
    attn_kernel<<<dim3(TL / 64, NB * NH), 256, 0, stream>>>(Q, K, V, O);
    oproj_kernel<<<dim3(MTOT / 64, TD / 64), 256, 0, stream>>>(O, Wo, bo, out);
}

// Round 2
// 317.629 us; speedup vs baseline: 4.8076x; 4.8076x over previous
//
#include <hip/hip_runtime.h>
#include <math.h>

#define TL 2048
#define TD 768
#define NH 12
#define HD 64
#define NB 4
#define MTOT (NB * TL)   // 8192

typedef __bf16 bf16;
typedef __attribute__((ext_vector_type(4))) __bf16 bf16x4;
typedef __attribute__((ext_vector_type(8))) __bf16 bf16x8;
typedef __attribute__((ext_vector_type(4))) float floatx4;

#define MFMA16(A, B, C) __builtin_amdgcn_mfma_f32_16x16x32_bf16(A, B, C, 0, 0, 0)

__device__ __forceinline__ void gl_lds16(const void* g, void* l) {
    __builtin_amdgcn_global_load_lds(
        (const __attribute__((address_space(1))) void*)g,
        (__attribute__((address_space(3))) void*)l, 16, 0, 0);
}

__device__ __forceinline__ floatx4 max4(floatx4 a, floatx4 b) {
    floatx4 r;
    r.x = fmaxf(a.x, b.x); r.y = fmaxf(a.y, b.y);
    r.z = fmaxf(a.z, b.z); r.w = fmaxf(a.w, b.w);
    return r;
}
__device__ __forceinline__ floatx4 exp4(floatx4 a) {
    floatx4 r;
    r.x = __expf(a.x); r.y = __expf(a.y); r.z = __expf(a.z); r.w = __expf(a.w);
    return r;
}
__device__ __forceinline__ floatx4 shflx4(floatx4 a, int m) {
    floatx4 r;
    r.x = __shfl_xor(a.x, m); r.y = __shfl_xor(a.y, m);
    r.z = __shfl_xor(a.z, m); r.w = __shfl_xor(a.w, m);
    return r;
}

// ---------------------------------------------------------------------------
// x fp32 -> bf16 (exact grid: 6291456 / (256*4) = 6144 blocks)
// ---------------------------------------------------------------------------
__global__ __launch_bounds__(256)
void cast_x_kernel(const float* __restrict__ x, bf16* __restrict__ xb)
{
    size_t i = ((size_t)blockIdx.x * 256 + threadIdx.x) * 4;
    float4 v = *(const float4*)(x + i);
    bf16x4 o;
    o[0] = (bf16)v.x; o[1] = (bf16)v.y; o[2] = (bf16)v.z; o[3] = (bf16)v.w;
    *(bf16x4*)(xb + i) = o;
}

// ---------------------------------------------------------------------------
// W [768,768] fp32 -> W^T bf16 (so GEMMs get contiguous-k B fragments)
// ---------------------------------------------------------------------------
__global__ __launch_bounds__(256)
void transw_kernel(const float* __restrict__ W0, const float* __restrict__ W1,
                   const float* __restrict__ W2, const float* __restrict__ W3,
                   bf16* __restrict__ T0, bf16* __restrict__ T1,
                   bf16* __restrict__ T2, bf16* __restrict__ T3)
{
    const int z = blockIdx.z;
    const float* W = z == 0 ? W0 : z == 1 ? W1 : z == 2 ? W2 : W3;
    bf16*       T = z == 0 ? T0 : z == 1 ? T1 : z == 2 ? T2 : T3;
    __shared__ float Ts[64][65];
    const int t = threadIdx.x;
    const int k0 = blockIdx.x * 64, n0 = blockIdx.y * 64;
    const int rr = t >> 4, cc = (t & 15) * 4;
#pragma unroll
    for (int i = 0; i < 4; ++i) {
        int row = rr + i * 16;
        float4 v = *(const float4*)(W + (size_t)(k0 + row) * TD + n0 + cc);
        Ts[row][cc] = v.x; Ts[row][cc + 1] = v.y;
        Ts[row][cc + 2] = v.z; Ts[row][cc + 3] = v.w;
    }
    __syncthreads();
#pragma unroll
    for (int i = 0; i < 4; ++i) {
        int n = rr + i * 16;
        bf16x4 pk;
#pragma unroll
        for (int j = 0; j < 4; ++j) pk[j] = (bf16)Ts[cc + j][n];
        *(bf16x4*)(T + (size_t)(n0 + n) * TD + k0 + cc) = pk;
    }
}

// ---------------------------------------------------------------------------
// QKV GEMM, m97-style: 128x128 tile, BK=32, 4 waves, 16x16x32 bf16 MFMA.
// Q,K -> [bh][l][64] bf16 (Q pre-scaled by 0.125); V -> [bh][d][2048] bf16.
// ---------------------------------------------------------------------------
__global__ __launch_bounds__(256)
void qkv_gemm(const bf16* __restrict__ xb,
              const bf16* __restrict__ Wqt, const bf16* __restrict__ Wkt,
              const bf16* __restrict__ Wvt,
              const float* __restrict__ bq, const float* __restrict__ bk,
              const float* __restrict__ bv,
              bf16* __restrict__ Q, bf16* __restrict__ K, bf16* __restrict__ Vt)
{
    __shared__ __align__(16) bf16 As[128 * 32];
    __shared__ __align__(16) bf16 Bs[128 * 32];

    const int t = threadIdx.x;
    const int lane = t & 63, w = t >> 6;
    const int quad = lane >> 4, l16 = lane & 15;
    const int m0 = blockIdx.x * 128;
    const int n0 = blockIdx.y * 128;
    const int which = blockIdx.z;
    const bf16*  W    = which == 0 ? Wqt : which == 1 ? Wkt : Wvt;
    const float* bias = which == 0 ? bq  : which == 1 ? bk  : bv;
    const float scale = which == 0 ? 0.125f : 1.0f;

    const int rm = (w >> 1) * 64, cn = (w & 1) * 64;

    floatx4 acc[4][4];
#pragma unroll
    for (int i = 0; i < 4; ++i)
#pragma unroll
        for (int j = 0; j < 4; ++j) acc[i][j] = (floatx4){0.f, 0.f, 0.f, 0.f};

    const int srow = t >> 2, sseg = (t & 3) * 8;
    const bf16* gA = xb + (size_t)(m0 + srow) * TD + sseg;
    const bf16* gB = W + (size_t)(n0 + srow) * TD + sseg;

    for (int kk = 0; kk < TD; kk += 32) {
        gl_lds16(gA + kk, As + t * 8);
        gl_lds16(gA + kk + (size_t)64 * TD, As + (t + 256) * 8);
        gl_lds16(gB + kk, Bs + t * 8);
        gl_lds16(gB + kk + (size_t)64 * TD, Bs + (t + 256) * 8);
        __syncthreads();
        bf16x8 af[4], bfr[4];
#pragma unroll
        for (int mb = 0; mb < 4; ++mb)
            af[mb] = *(const bf16x8*)&As[(rm + mb * 16 + l16) * 32 + quad * 8];
#pragma unroll
        for (int nb = 0; nb < 4; ++nb)
            bfr[nb] = *(const bf16x8*)&Bs[(cn + nb * 16 + l16) * 32 + quad * 8];
#pragma unroll
        for (int mb = 0; mb < 4; ++mb)
#pragma unroll
            for (int nb = 0; nb < 4; ++nb)
                acc[mb][nb] = MFMA16(af[mb], bfr[nb], acc[mb][nb]);
        __syncthreads();
    }

#pragma unroll
    for (int mb = 0; mb < 4; ++mb) {
#pragma unroll
        for (int nb = 0; nb < 4; ++nb) {
            const int n = n0 + cn + nb * 16 + l16;
            const int h = n >> 6, d = n & 63;
            const float bsc = bias[n] * scale;
            const int mBase = m0 + rm + mb * 16 + quad * 4;
            const int b = mBase >> 11;
            const int l0 = mBase & (TL - 1);
            const int bh = b * NH + h;
            if (which < 2) {
                bf16* outp = (which == 0 ? Q : K) + ((size_t)bh * TL + l0) * HD + d;
#pragma unroll
                for (int r = 0; r < 4; ++r)
                    outp[(size_t)r * HD] = (bf16)(acc[mb][nb][r] * scale + bsc);
            } else {
                bf16x4 pk;
#pragma unroll
                for (int r = 0; r < 4; ++r) pk[r] = (bf16)(acc[mb][nb][r] + bsc);
                *(bf16x4*)(Vt + ((size_t)bh * HD + d) * TL + l0) = pk;
            }
        }
    }
}

// ---------------------------------------------------------------------------
// MFMA flash attention. Block: 128 q-rows x one bh; 4 waves, 32 q-rows each.
// K-steps of 64 keys. In-register online softmax on C-layout; P through
// per-wave LDS into A-layout for PV (m120-verified pattern).
// ---------------------------------------------------------------------------
__global__ __launch_bounds__(256)
void attn_kernel(const bf16* __restrict__ Q, const bf16* __restrict__ K,
                 const bf16* __restrict__ Vt, bf16* __restrict__ O)
{
    __shared__ __align__(16) bf16 Ks[64 * 72];       // [key][d], stride 72
    __shared__ __align__(16) bf16 Vs[64 * 72];       // [d][key], stride 72
    __shared__ __align__(16) bf16 Ps[4 * 32 * 72];   // per-wave P [qrow][key]

    const int t = threadIdx.x;
    const int lane = t & 63, w = t >> 6;
    const int quad = lane >> 4, l16 = lane & 15;
    const int q0 = blockIdx.x * 128;
    const int bh = blockIdx.y;
    const bf16* Qb = Q + (size_t)bh * TL * HD;
    const bf16* Kb = K + (size_t)bh * TL * HD;
    const bf16* Vb = Vt + (size_t)bh * HD * TL;
    bf16* Pw = Ps + w * (32 * 72);

    const int qw = q0 + w * 32;
    bf16x8 qf[2][2];
#pragma unroll
    for (int mb = 0; mb < 2; ++mb)
#pragma unroll
        for (int ks = 0; ks < 2; ++ks)
            qf[mb][ks] = *(const bf16x8*)(Qb + (size_t)(qw + mb * 16 + l16) * HD
                                          + ks * 32 + quad * 8);

    floatx4 mrow[2], lrow[2], o[2][4];
#pragma unroll
    for (int mb = 0; mb < 2; ++mb) {
        mrow[mb] = (floatx4){-1e30f, -1e30f, -1e30f, -1e30f};
        lrow[mb] = (floatx4){0.f, 0.f, 0.f, 0.f};
#pragma unroll
        for (int db = 0; db < 4; ++db) o[mb][db] = (floatx4){0.f, 0.f, 0.f, 0.f};
    }

    const int sr = t >> 3, ss = (t & 7) * 8;

    for (int kt = 0; kt < TL / 64; ++kt) {
        const int k0 = kt * 64;
        __syncthreads();
#pragma unroll
        for (int i = 0; i < 2; ++i) {
            int row = sr + i * 32;
            *(float4*)&Ks[row * 72 + ss] =
                *(const float4*)(Kb + (size_t)(k0 + row) * HD + ss);
            *(float4*)&Vs[row * 72 + ss] =
                *(const float4*)(Vb + (size_t)row * TL + k0 + ss);
        }
        __syncthreads();

        // S = Q K^T (Q pre-scaled by 1/8)
        floatx4 s[2][4];
#pragma unroll
        for (int nb = 0; nb < 4; ++nb) {
            bf16x8 kf0 = *(const bf16x8*)&Ks[(nb * 16 + l16) * 72 + quad * 8];
            bf16x8 kf1 = *(const bf16x8*)&Ks[(nb * 16 + l16) * 72 + 32 + quad * 8];
#pragma unroll
            for (int mb = 0; mb < 2; ++mb) {
                floatx4 a = (floatx4){0.f, 0.f, 0.f, 0.f};
                a = MFMA16(qf[mb][0], kf0, a);
                a = MFMA16(qf[mb][1], kf1, a);
                s[mb][nb] = a;
            }
        }

        // online softmax per row (row = quad*4 + reg; reduce over 16-lane quad)
#pragma unroll
        for (int mb = 0; mb < 2; ++mb) {
            floatx4 mx = s[mb][0];
#pragma unroll
            for (int nb = 1; nb < 4; ++nb) mx = max4(mx, s[mb][nb]);
#pragma unroll
            for (int msk = 1; msk < 16; msk <<= 1) mx = max4(mx, shflx4(mx, msk));
            floatx4 mnew = max4(mrow[mb], mx);
            floatx4 alpha = exp4(mrow[mb] - mnew);
            mrow[mb] = mnew;
            floatx4 ssum = (floatx4){0.f, 0.f, 0.f, 0.f};
#pragma unroll
            for (int nb = 0; nb < 4; ++nb) {
                floatx4 p = exp4(s[mb][nb] - mnew);
                s[mb][nb] = p;
                ssum += p;
            }
#pragma unroll
            for (int msk = 1; msk < 16; msk <<= 1) ssum += shflx4(ssum, msk);
            lrow[mb] = lrow[mb] * alpha + ssum;
#pragma unroll
            for (int db = 0; db < 4; ++db) o[mb][db] *= alpha;
#pragma unroll
            for (int nb = 0; nb < 4; ++nb)
#pragma unroll
                for (int r = 0; r < 4; ++r)
                    Pw[(mb * 16 + quad * 4 + r) * 72 + nb * 16 + l16] =
                        (bf16)s[mb][nb][r];
        }

        // O += P V
#pragma unroll
        for (int ks = 0; ks < 2; ++ks) {
            bf16x8 pf[2];
#pragma unroll
            for (int mb = 0; mb < 2; ++mb)
                pf[mb] = *(const bf16x8*)&Pw[(mb * 16 + l16) * 72 + ks * 32 + quad * 8];
#pragma unroll
            for (int db = 0; db < 4; ++db) {
                bf16x8 vf = *(const bf16x8*)&Vs[(db * 16 + l16) * 72 + ks * 32 + quad * 8];
#pragma unroll
                for (int mb = 0; mb < 2; ++mb)
                    o[mb][db] = MFMA16(pf[mb], vf, o[mb][db]);
            }
        }
    }

    // epilogue: normalize, write O bf16 in [b][l][768]
    const int b = bh / NH, h = bh % NH;
#pragma unroll
    for (int mb = 0; mb < 2; ++mb) {
        floatx4 inv;
        inv.x = 1.0f / lrow[mb].x; inv.y = 1.0f / lrow[mb].y;
        inv.z = 1.0f / lrow[mb].z; inv.w = 1.0f / lrow[mb].w;
#pragma unroll
        for (int db = 0; db < 4; ++db)
#pragma unroll
            for (int r = 0; r < 4; ++r) {
                int l = qw + mb * 16 + quad * 4 + r;
                O[((size_t)b * TL + l) * TD + h * HD + db * 16 + l16] =
                    (bf16)(o[mb][db][r] * inv[r]);
            }
    }
}

// ---------------------------------------------------------------------------
// Output projection: out fp32 = O_bf16 @ Wo + bo (same m97 GEMM structure)
// ---------------------------------------------------------------------------
__global__ __launch_bounds__(256)
void oproj_gemm(const bf16* __restrict__ A, const bf16* __restrict__ Wt,
                const float* __restrict__ bo, float* __restrict__ out)
{
    __shared__ __align__(16) bf16 As[128 * 32];
    __shared__ __align__(16) bf16 Bs[128 * 32];

    const int t = threadIdx.x;
    const int lane = t & 63, w = t >> 6;
    const int quad = lane >> 4, l16 = lane & 15;
    const int m0 = blockIdx.x * 128;
    const int n0 = blockIdx.y * 128;
    const int rm = (w >> 1) * 64, cn = (w & 1) * 64;

    floatx4 acc[4][4];
#pragma unroll
    for (int i = 0; i < 4; ++i)
#pragma unroll
        for (int j = 0; j < 4; ++j) acc[i][j] = (floatx4){0.f, 0.f, 0.f, 0.f};

    const int srow = t >> 2, sseg = (t & 3) * 8;
    const bf16* gA = A + (size_t)(m0 + srow) * TD + sseg;
    const bf16* gB = Wt + (size_t)(n0 + srow) * TD + sseg;

    for (int kk = 0; kk < TD; kk += 32) {
        gl_lds16(gA + kk, As + t * 8);
        gl_lds16(gA + kk + (size_t)64 * TD, As + (t + 256) * 8);
        gl_lds16(gB + kk, Bs + t * 8);
        gl_lds16(gB + kk + (size_t)64 * TD, Bs + (t + 256) * 8);
        __syncthreads();
        bf16x8 af[4], bfr[4];
#pragma unroll
        for (int mb = 0; mb < 4; ++mb)
            af[mb] = *(const bf16x8*)&As[(rm + mb * 16 + l16) * 32 + quad * 8];
#pragma unroll
        for (int nb = 0; nb < 4; ++nb)
            bfr[nb] = *(const bf16x8*)&Bs[(cn + nb * 16 + l16) * 32 + quad * 8];
#pragma unroll
        for (int mb = 0; mb < 4; ++mb)
#pragma unroll
            for (int nb = 0; nb < 4; ++nb)
                acc[mb][nb] = MFMA16(af[mb], bfr[nb], acc[mb][nb]);
        __syncthreads();
    }

#pragma unroll
    for (int mb = 0; mb < 4; ++mb) {
#pragma unroll
        for (int nb = 0; nb < 4; ++nb) {
            const int n = n0 + cn + nb * 16 + l16;
            const float bb = bo[n];
            const int mBase = m0 + rm + mb * 16 + quad * 4;
            float* outp = out + (size_t)mBase * TD + n;
#pragma unroll
            for (int r = 0; r < 4; ++r)
                outp[(size_t)r * TD] = acc[mb][nb][r] + bb;
        }
    }
}

// ---------------------------------------------------------------------------
extern "C" void kernel_launch(void* const* d_in, const int* in_sizes, int n_in,
                              void* d_out, int out_size, void* d_ws, size_t ws_size,
                              hipStream_t stream)
{
    const float* x  = (const float*)d_in[0];
    const float* Wq = (const float*)d_in[1];
    const float* bq = (const float*)d_in[2];
    const float* Wk = (const float*)d_in[3];
    const float* bk = (const float*)d_in[4];
    const float* Wv = (const float*)d_in[5];
    const float* bv = (const float*)d_in[6];
    const float* Wo = (const float*)d_in[7];
    const float* bo = (const float*)d_in[8];

    const size_t NXE = (size_t)MTOT * TD;    // 6,291,456
    const size_t NWE = (size_t)TD * TD;      // 589,824

    bf16* xb  = (bf16*)d_ws;
    bf16* Wqt = xb + NXE;
    bf16* Wkt = Wqt + NWE;
    bf16* Wvt = Wkt + NWE;
    bf16* Wot = Wvt + NWE;
    bf16* Qb  = Wot + NWE;
    bf16* Kb  = Qb + NXE;
    bf16* Vtb = Kb + NXE;
    bf16* Ob  = Vtb + NXE;

    cast_x_kernel<<<6144, 256, 0, stream>>>(x, xb);
    transw_kernel<<<dim3(12, 12, 4), 256, 0, stream>>>(Wq, Wk, Wv, Wo,
                                                       Wqt, Wkt, Wvt, Wot);
    qkv_gemm<<<dim3(MTOT / 128, TD / 128, 3), 256, 0, stream>>>(
        xb, Wqt, Wkt, Wvt, bq, bk, bv, Qb, Kb, Vtb);
    attn_kernel<<<dim3(TL / 128, NB * NH), 256, 0, stream>>>(Qb, Kb, Vtb, Ob);
    oproj_gemm<<<dim3(MTOT / 128, TD / 128), 256, 0, stream>>>(Ob, Wot, bo,
                                                               (float*)d_out);
}

// Round 3
// 242.152 us; speedup vs baseline: 6.3061x; 1.3117x over previous
//
#include <hip/hip_runtime.h>
#include <math.h>

#define TL 2048
#define TD 768
#define NH 12
#define HD 64
#define NB 4
#define MTOT (NB * TL)   // 8192

typedef __bf16 bf16;
typedef __attribute__((ext_vector_type(4))) __bf16 bf16x4;
typedef __attribute__((ext_vector_type(8))) __bf16 bf16x8;
typedef __attribute__((ext_vector_type(4))) float floatx4;

// Q pre-scale: 1/sqrt(64) * log2(e)  (softmax computed in exp2 domain)
#define QSCALE 0.18033688011112042f

#define MFMA16(A, B, C) __builtin_amdgcn_mfma_f32_16x16x32_bf16(A, B, C, 0, 0, 0)

__device__ __forceinline__ void gl_lds16(const void* g, void* l) {
    __builtin_amdgcn_global_load_lds(
        (const __attribute__((address_space(1))) void*)g,
        (__attribute__((address_space(3))) void*)l, 16, 0, 0);
}

__device__ __forceinline__ floatx4 exp2x4(floatx4 a) {
    floatx4 r;
    r.x = __builtin_amdgcn_exp2f(a.x);
    r.y = __builtin_amdgcn_exp2f(a.y);
    r.z = __builtin_amdgcn_exp2f(a.z);
    r.w = __builtin_amdgcn_exp2f(a.w);
    return r;
}
__device__ __forceinline__ floatx4 shflx4(floatx4 a, int m) {
    floatx4 r;
    r.x = __shfl_xor(a.x, m); r.y = __shfl_xor(a.y, m);
    r.z = __shfl_xor(a.z, m); r.w = __shfl_xor(a.w, m);
    return r;
}

// ---------------------------------------------------------------------------
// x fp32 -> bf16
// ---------------------------------------------------------------------------
__global__ __launch_bounds__(256)
void cast_x_kernel(const float* __restrict__ x, bf16* __restrict__ xb)
{
    size_t i = ((size_t)blockIdx.x * 256 + threadIdx.x) * 4;
    float4 v = *(const float4*)(x + i);
    bf16x4 o;
    o[0] = (bf16)v.x; o[1] = (bf16)v.y; o[2] = (bf16)v.z; o[3] = (bf16)v.w;
    *(bf16x4*)(xb + i) = o;
}

// ---------------------------------------------------------------------------
// W [768,768] fp32 -> W^T bf16
// ---------------------------------------------------------------------------
__global__ __launch_bounds__(256)
void transw_kernel(const float* __restrict__ W0, const float* __restrict__ W1,
                   const float* __restrict__ W2, const float* __restrict__ W3,
                   bf16* __restrict__ T0, bf16* __restrict__ T1,
                   bf16* __restrict__ T2, bf16* __restrict__ T3)
{
    const int z = blockIdx.z;
    const float* W = z == 0 ? W0 : z == 1 ? W1 : z == 2 ? W2 : W3;
    bf16*       T = z == 0 ? T0 : z == 1 ? T1 : z == 2 ? T2 : T3;
    __shared__ float Ts[64][65];
    const int t = threadIdx.x;
    const int k0 = blockIdx.x * 64, n0 = blockIdx.y * 64;
    const int rr = t >> 4, cc = (t & 15) * 4;
#pragma unroll
    for (int i = 0; i < 4; ++i) {
        int row = rr + i * 16;
        float4 v = *(const float4*)(W + (size_t)(k0 + row) * TD + n0 + cc);
        Ts[row][cc] = v.x; Ts[row][cc + 1] = v.y;
        Ts[row][cc + 2] = v.z; Ts[row][cc + 3] = v.w;
    }
    __syncthreads();
#pragma unroll
    for (int i = 0; i < 4; ++i) {
        int n = rr + i * 16;
        bf16x4 pk;
#pragma unroll
        for (int j = 0; j < 4; ++j) pk[j] = (bf16)Ts[cc + j][n];
        *(bf16x4*)(T + (size_t)(n0 + n) * TD + k0 + cc) = pk;
    }
}

// ---------------------------------------------------------------------------
// QKV GEMM, 128x128 tile, BK=32. Epilogue bounces C tiles through per-wave
// LDS so all global stores are coalesced 16B/lane.
// Q,K -> [bh][l][64] bf16 (Q pre-scaled by QSCALE); V -> [bh][d][2048] bf16.
// ---------------------------------------------------------------------------
__global__ __launch_bounds__(256)
void qkv_gemm(const bf16* __restrict__ xb,
              const bf16* __restrict__ Wqt, const bf16* __restrict__ Wkt,
              const bf16* __restrict__ Wvt,
              const float* __restrict__ bq, const float* __restrict__ bk,
              const float* __restrict__ bv,
              bf16* __restrict__ Q, bf16* __restrict__ K, bf16* __restrict__ Vt)
{
    __shared__ __align__(16) bf16 As[128 * 32];
    __shared__ __align__(16) bf16 Bs[128 * 32];
    __shared__ __align__(16) bf16 Eb[4][16 * 72];   // per-wave epilogue bounce

    const int t = threadIdx.x;
    const int lane = t & 63, w = t >> 6;
    const int quad = lane >> 4, l16 = lane & 15;
    const int m0 = blockIdx.x * 128;
    const int n0 = blockIdx.y * 128;
    const int which = blockIdx.z;
    const bf16*  W    = which == 0 ? Wqt : which == 1 ? Wkt : Wvt;
    const float* bias = which == 0 ? bq  : which == 1 ? bk  : bv;
    const float scale = which == 0 ? QSCALE : 1.0f;

    const int rm = (w >> 1) * 64, cn = (w & 1) * 64;

    floatx4 acc[4][4];
#pragma unroll
    for (int i = 0; i < 4; ++i)
#pragma unroll
        for (int j = 0; j < 4; ++j) acc[i][j] = (floatx4){0.f, 0.f, 0.f, 0.f};

    const int srow = t >> 2, sseg = (t & 3) * 8;
    const bf16* gA = xb + (size_t)(m0 + srow) * TD + sseg;
    const bf16* gB = W + (size_t)(n0 + srow) * TD + sseg;

    for (int kk = 0; kk < TD; kk += 32) {
        gl_lds16(gA + kk, As + t * 8);
        gl_lds16(gA + kk + (size_t)64 * TD, As + (t + 256) * 8);
        gl_lds16(gB + kk, Bs + t * 8);
        gl_lds16(gB + kk + (size_t)64 * TD, Bs + (t + 256) * 8);
        __syncthreads();
        bf16x8 af[4], bfr[4];
#pragma unroll
        for (int mb = 0; mb < 4; ++mb)
            af[mb] = *(const bf16x8*)&As[(rm + mb * 16 + l16) * 32 + quad * 8];
#pragma unroll
        for (int nb = 0; nb < 4; ++nb)
            bfr[nb] = *(const bf16x8*)&Bs[(cn + nb * 16 + l16) * 32 + quad * 8];
#pragma unroll
        for (int mb = 0; mb < 4; ++mb)
#pragma unroll
            for (int nb = 0; nb < 4; ++nb)
                acc[mb][nb] = MFMA16(af[mb], bfr[nb], acc[mb][nb]);
        __syncthreads();
    }

    // bias (scaled) per nb, fixed for this lane
    float bsc[4];
#pragma unroll
    for (int nb = 0; nb < 4; ++nb)
        bsc[nb] = bias[n0 + cn + nb * 16 + l16] * scale;

    const int token0 = m0 + rm;
    const int b  = token0 >> 11;
    const int l0 = token0 & (TL - 1);
    const int h  = (n0 + cn) >> 6;
    const int bh = b * NH + h;
    bf16* Ew = Eb[w];

    if (which < 2) {
        bf16* gp = (which == 0 ? Q : K) + ((size_t)bh * TL + l0) * HD;
#pragma unroll
        for (int mb = 0; mb < 4; ++mb) {
            // scatter 16 tokens x 64 d into LDS [token][d] (stride 72)
#pragma unroll
            for (int nb = 0; nb < 4; ++nb)
#pragma unroll
                for (int r = 0; r < 4; ++r)
                    Ew[(quad * 4 + r) * 72 + nb * 16 + l16] =
                        (bf16)(acc[mb][nb][r] * scale + bsc[nb]);
            // coalesced store: 16 token rows x 128B
#pragma unroll
            for (int i = 0; i < 2; ++i) {
                int row = i * 8 + (lane >> 3), seg = lane & 7;
                bf16x8 v = *(const bf16x8*)&Ew[row * 72 + seg * 8];
                *(bf16x8*)(gp + (size_t)(mb * 16 + row) * HD + seg * 8) = v;
            }
        }
    } else {
#pragma unroll
        for (int nb = 0; nb < 4; ++nb) {
            // scatter 16 d x 64 tokens into LDS [d][token] (stride 72)
#pragma unroll
            for (int mb = 0; mb < 4; ++mb) {
                bf16x4 pk;
#pragma unroll
                for (int r = 0; r < 4; ++r) pk[r] = (bf16)(acc[mb][nb][r] + bsc[nb]);
                *(bf16x4*)&Ew[l16 * 72 + mb * 16 + quad * 4] = pk;
            }
            // coalesced store: 16 d rows x 128B into Vt[bh][d][token]
#pragma unroll
            for (int i = 0; i < 2; ++i) {
                int row = i * 8 + (lane >> 3), seg = lane & 7;
                bf16x8 v = *(const bf16x8*)&Ew[row * 72 + seg * 8];
                *(bf16x8*)(Vt + ((size_t)bh * HD + nb * 16 + row) * TL + l0 + seg * 8) = v;
            }
        }
    }
}

// ---------------------------------------------------------------------------
// MFMA flash attention, no-running-max softmax (exp2 domain; Q pre-scaled).
// Block: 128 q-rows x one bh; 4 waves, 32 q-rows each. Row-sum kept as
// per-lane partials, reduced once in the epilogue.
// ---------------------------------------------------------------------------
__global__ __launch_bounds__(256)
void attn_kernel(const bf16* __restrict__ Q, const bf16* __restrict__ K,
                 const bf16* __restrict__ Vt, bf16* __restrict__ O)
{
    __shared__ __align__(16) bf16 Ks[64 * 72];       // [key][d], stride 72
    __shared__ __align__(16) bf16 Vs[64 * 72];       // [d][key], stride 72
    __shared__ __align__(16) bf16 Ps[4 * 32 * 72];   // per-wave P [qrow][key]

    const int t = threadIdx.x;
    const int lane = t & 63, w = t >> 6;
    const int quad = lane >> 4, l16 = lane & 15;

    // XCD-aware swizzle: blocks on the same XCD (n%8) share one bh's K/V
    const int n = blockIdx.y * gridDim.x + blockIdx.x;   // 0..767
    const int xcd = n & 7, s = n >> 3;                   // s: 0..95
    const int bh = xcd * 6 + (s >> 4);
    const int q0 = (s & 15) * 128;

    const bf16* Qb = Q + (size_t)bh * TL * HD;
    const bf16* Kb = K + (size_t)bh * TL * HD;
    const bf16* Vb = Vt + (size_t)bh * HD * TL;
    bf16* Pw = Ps + w * (32 * 72);

    const int qw = q0 + w * 32;
    bf16x8 qf[2][2];
#pragma unroll
    for (int mb = 0; mb < 2; ++mb)
#pragma unroll
        for (int ks = 0; ks < 2; ++ks)
            qf[mb][ks] = *(const bf16x8*)(Qb + (size_t)(qw + mb * 16 + l16) * HD
                                          + ks * 32 + quad * 8);

    floatx4 lrow[2], o[2][4];
#pragma unroll
    for (int mb = 0; mb < 2; ++mb) {
        lrow[mb] = (floatx4){0.f, 0.f, 0.f, 0.f};
#pragma unroll
        for (int db = 0; db < 4; ++db) o[mb][db] = (floatx4){0.f, 0.f, 0.f, 0.f};
    }

    const int sr = t >> 3, ss = (t & 7) * 8;

    for (int kt = 0; kt < TL / 64; ++kt) {
        const int k0 = kt * 64;
        __syncthreads();
#pragma unroll
        for (int i = 0; i < 2; ++i) {
            int row = sr + i * 32;
            *(float4*)&Ks[row * 72 + ss] =
                *(const float4*)(Kb + (size_t)(k0 + row) * HD + ss);
            *(float4*)&Vs[row * 72 + ss] =
                *(const float4*)(Vb + (size_t)row * TL + k0 + ss);
        }
        __syncthreads();

        // S = Q K^T (Q pre-scaled so P = 2^S is softmax numerator)
        floatx4 s2[2][4];
#pragma unroll
        for (int nb = 0; nb < 4; ++nb) {
            bf16x8 kf0 = *(const bf16x8*)&Ks[(nb * 16 + l16) * 72 + quad * 8];
            bf16x8 kf1 = *(const bf16x8*)&Ks[(nb * 16 + l16) * 72 + 32 + quad * 8];
#pragma unroll
            for (int mb = 0; mb < 2; ++mb) {
                floatx4 a = (floatx4){0.f, 0.f, 0.f, 0.f};
                a = MFMA16(qf[mb][0], kf0, a);
                a = MFMA16(qf[mb][1], kf1, a);
                s2[mb][nb] = a;
            }
        }

        // P = 2^S; accumulate per-lane row-sum partials; stage P to LDS
#pragma unroll
        for (int mb = 0; mb < 2; ++mb) {
#pragma unroll
            for (int nb = 0; nb < 4; ++nb) {
                floatx4 p = exp2x4(s2[mb][nb]);
                lrow[mb] += p;
#pragma unroll
                for (int r = 0; r < 4; ++r)
                    Pw[(mb * 16 + quad * 4 + r) * 72 + nb * 16 + l16] = (bf16)p[r];
            }
        }

        // O += P V
#pragma unroll
        for (int ks = 0; ks < 2; ++ks) {
            bf16x8 pf[2];
#pragma unroll
            for (int mb = 0; mb < 2; ++mb)
                pf[mb] = *(const bf16x8*)&Pw[(mb * 16 + l16) * 72 + ks * 32 + quad * 8];
#pragma unroll
            for (int db = 0; db < 4; ++db) {
                bf16x8 vf = *(const bf16x8*)&Vs[(db * 16 + l16) * 72 + ks * 32 + quad * 8];
#pragma unroll
                for (int mb = 0; mb < 2; ++mb)
                    o[mb][db] = MFMA16(pf[mb], vf, o[mb][db]);
            }
        }
    }

    // epilogue: reduce row-sums across the 16-lane group once, normalize, store
    const int b = bh / NH, h = bh % NH;
#pragma unroll
    for (int mb = 0; mb < 2; ++mb) {
#pragma unroll
        for (int msk = 1; msk < 16; msk <<= 1) lrow[mb] += shflx4(lrow[mb], msk);
        floatx4 inv;
        inv.x = 1.0f / lrow[mb].x; inv.y = 1.0f / lrow[mb].y;
        inv.z = 1.0f / lrow[mb].z; inv.w = 1.0f / lrow[mb].w;
#pragma unroll
        for (int db = 0; db < 4; ++db)
#pragma unroll
            for (int r = 0; r < 4; ++r) {
                int l = qw + mb * 16 + quad * 4 + r;
                O[((size_t)b * TL + l) * TD + h * HD + db * 16 + l16] =
                    (bf16)(o[mb][db][r] * inv[r]);
            }
    }
}

// ---------------------------------------------------------------------------
// Output projection: out fp32 = O_bf16 @ Wo + bo, LDS-bounce epilogue.
// ---------------------------------------------------------------------------
__global__ __launch_bounds__(256)
void oproj_gemm(const bf16* __restrict__ A, const bf16* __restrict__ Wt,
                const float* __restrict__ bo, float* __restrict__ out)
{
    __shared__ __align__(16) bf16 As[128 * 32];
    __shared__ __align__(16) bf16 Bs[128 * 32];
    __shared__ __align__(16) float Ef[4][16 * 68];   // per-wave f32 bounce

    const int t = threadIdx.x;
    const int lane = t & 63, w = t >> 6;
    const int quad = lane >> 4, l16 = lane & 15;
    const int m0 = blockIdx.x * 128;
    const int n0 = blockIdx.y * 128;
    const int rm = (w >> 1) * 64, cn = (w & 1) * 64;

    floatx4 acc[4][4];
#pragma unroll
    for (int i = 0; i < 4; ++i)
#pragma unroll
        for (int j = 0; j < 4; ++j) acc[i][j] = (floatx4){0.f, 0.f, 0.f, 0.f};

    const int srow = t >> 2, sseg = (t & 3) * 8;
    const bf16* gA = A + (size_t)(m0 + srow) * TD + sseg;
    const bf16* gB = Wt + (size_t)(n0 + srow) * TD + sseg;

    for (int kk = 0; kk < TD; kk += 32) {
        gl_lds16(gA + kk, As + t * 8);
        gl_lds16(gA + kk + (size_t)64 * TD, As + (t + 256) * 8);
        gl_lds16(gB + kk, Bs + t * 8);
        gl_lds16(gB + kk + (size_t)64 * TD, Bs + (t + 256) * 8);
        __syncthreads();
        bf16x8 af[4], bfr[4];
#pragma unroll
        for (int mb = 0; mb < 4; ++mb)
            af[mb] = *(const bf16x8*)&As[(rm + mb * 16 + l16) * 32 + quad * 8];
#pragma unroll
        for (int nb = 0; nb < 4; ++nb)
            bfr[nb] = *(const bf16x8*)&Bs[(cn + nb * 16 + l16) * 32 + quad * 8];
#pragma unroll
        for (int mb = 0; mb < 4; ++mb)
#pragma unroll
            for (int nb = 0; nb < 4; ++nb)
                acc[mb][nb] = MFMA16(af[mb], bfr[nb], acc[mb][nb]);
        __syncthreads();
    }

    float bb[4];
#pragma unroll
    for (int nb = 0; nb < 4; ++nb) bb[nb] = bo[n0 + cn + nb * 16 + l16];

    float* Ew = Ef[w];
#pragma unroll
    for (int mb = 0; mb < 4; ++mb) {
#pragma unroll
        for (int nb = 0; nb < 4; ++nb)
#pragma unroll
            for (int r = 0; r < 4; ++r)
                Ew[(quad * 4 + r) * 68 + nb * 16 + l16] = acc[mb][nb][r] + bb[nb];
#pragma unroll
        for (int i = 0; i < 4; ++i) {
            int row = i * 4 + (lane >> 4), seg = lane & 15;
            float4 v = *(const float4*)&Ew[row * 68 + seg * 4];
            *(float4*)(out + (size_t)(m0 + rm + mb * 16 + row) * TD + n0 + cn + seg * 4) = v;
        }
    }
}

// ---------------------------------------------------------------------------
extern "C" void kernel_launch(void* const* d_in, const int* in_sizes, int n_in,
                              void* d_out, int out_size, void* d_ws, size_t ws_size,
                              hipStream_t stream)
{
    const float* x  = (const float*)d_in[0];
    const float* Wq = (const float*)d_in[1];
    const float* bq = (const float*)d_in[2];
    const float* Wk = (const float*)d_in[3];
    const float* bk = (const float*)d_in[4];
    const float* Wv = (const float*)d_in[5];
    const float* bv = (const float*)d_in[6];
    const float* Wo = (const float*)d_in[7];
    const float* bo = (const float*)d_in[8];

    const size_t NXE = (size_t)MTOT * TD;    // 6,291,456
    const size_t NWE = (size_t)TD * TD;      // 589,824

    bf16* xb  = (bf16*)d_ws;
    bf16* Wqt = xb + NXE;
    bf16* Wkt = Wqt + NWE;
    bf16* Wvt = Wkt + NWE;
    bf16* Wot = Wvt + NWE;
    bf16* Qb  = Wot + NWE;
    bf16* Kb  = Qb + NXE;
    bf16* Vtb = Kb + NXE;
    bf16* Ob  = Vtb + NXE;

    cast_x_kernel<<<6144, 256, 0, stream>>>(x, xb);
    transw_kernel<<<dim3(12, 12, 4), 256, 0, stream>>>(Wq, Wk, Wv, Wo,
                                                       Wqt, Wkt, Wvt, Wot);
    qkv_gemm<<<dim3(MTOT / 128, TD / 128, 3), 256, 0, stream>>>(
        xb, Wqt, Wkt, Wvt, bq, bk, bv, Qb, Kb, Vtb);
    attn_kernel<<<dim3(TL / 128, NB * NH), 256, 0, stream>>>(Qb, Kb, Vtb, Ob);
    oproj_gemm<<<dim3(MTOT / 128, TD / 128), 256, 0, stream>>>(Ob, Wot, bo,
                                                               (float*)d_out);
}

// Round 4
// 218.568 us; speedup vs baseline: 6.9866x; 1.1079x over previous
//
#include <hip/hip_runtime.h>
#include <math.h>

#define TL 2048
#define TD 768
#define NH 12
#define HD 64
#define NB 4
#define MTOT (NB * TL)   // 8192

typedef __bf16 bf16;
typedef __attribute__((ext_vector_type(4))) __bf16 bf16x4;
typedef __attribute__((ext_vector_type(8))) __bf16 bf16x8;
typedef __attribute__((ext_vector_type(4))) float floatx4;

// Q pre-scale: 1/sqrt(64) * log2(e)  (softmax computed in exp2 domain)
#define QSCALE 0.18033688011112042f

#define MFMA16(A, B, C) __builtin_amdgcn_mfma_f32_16x16x32_bf16(A, B, C, 0, 0, 0)

__device__ __forceinline__ void gl_lds16(const void* g, void* l) {
    __builtin_amdgcn_global_load_lds(
        (const __attribute__((address_space(1))) void*)g,
        (__attribute__((address_space(3))) void*)l, 16, 0, 0);
}

__device__ __forceinline__ floatx4 exp2x4(floatx4 a) {
    floatx4 r;
    r.x = __builtin_amdgcn_exp2f(a.x);
    r.y = __builtin_amdgcn_exp2f(a.y);
    r.z = __builtin_amdgcn_exp2f(a.z);
    r.w = __builtin_amdgcn_exp2f(a.w);
    return r;
}

// key -> LDS row permutation so that QK^T's C-layout registers coincide with
// PV's A-fragment layout (groups of 8 consecutive keys per quad).
//   key bits [a c1 c0 b d1 d0] -> lds_row bits [a b c1 c0 d1 d0]
__device__ __forceinline__ int kperm(int key) {
    return (key & 35) | ((key >> 2) & 1) << 4 | ((key >> 3) & 3) << 2;
}

// ---------------------------------------------------------------------------
// x fp32 -> bf16
// ---------------------------------------------------------------------------
__global__ __launch_bounds__(256)
void cast_x_kernel(const float* __restrict__ x, bf16* __restrict__ xb)
{
    size_t i = ((size_t)blockIdx.x * 256 + threadIdx.x) * 4;
    float4 v = *(const float4*)(x + i);
    bf16x4 o;
    o[0] = (bf16)v.x; o[1] = (bf16)v.y; o[2] = (bf16)v.z; o[3] = (bf16)v.w;
    *(bf16x4*)(xb + i) = o;
}

// ---------------------------------------------------------------------------
// W [768,768] fp32 -> W^T bf16
// ---------------------------------------------------------------------------
__global__ __launch_bounds__(256)
void transw_kernel(const float* __restrict__ W0, const float* __restrict__ W1,
                   const float* __restrict__ W2, const float* __restrict__ W3,
                   bf16* __restrict__ T0, bf16* __restrict__ T1,
                   bf16* __restrict__ T2, bf16* __restrict__ T3)
{
    const int z = blockIdx.z;
    const float* W = z == 0 ? W0 : z == 1 ? W1 : z == 2 ? W2 : W3;
    bf16*       T = z == 0 ? T0 : z == 1 ? T1 : z == 2 ? T2 : T3;
    __shared__ float Ts[64][65];
    const int t = threadIdx.x;
    const int k0 = blockIdx.x * 64, n0 = blockIdx.y * 64;
    const int rr = t >> 4, cc = (t & 15) * 4;
#pragma unroll
    for (int i = 0; i < 4; ++i) {
        int row = rr + i * 16;
        float4 v = *(const float4*)(W + (size_t)(k0 + row) * TD + n0 + cc);
        Ts[row][cc] = v.x; Ts[row][cc + 1] = v.y;
        Ts[row][cc + 2] = v.z; Ts[row][cc + 3] = v.w;
    }
    __syncthreads();
#pragma unroll
    for (int i = 0; i < 4; ++i) {
        int n = rr + i * 16;
        bf16x4 pk;
#pragma unroll
        for (int j = 0; j < 4; ++j) pk[j] = (bf16)Ts[cc + j][n];
        *(bf16x4*)(T + (size_t)(n0 + n) * TD + k0 + cc) = pk;
    }
}

// ---------------------------------------------------------------------------
// QKV GEMM, 128x128 tile, BK=32, LDS-bounce coalesced epilogue.
// Q,K -> [bh][l][64] bf16 (Q pre-scaled by QSCALE); V -> [bh][d][2048] bf16.
// ---------------------------------------------------------------------------
__global__ __launch_bounds__(256)
void qkv_gemm(const bf16* __restrict__ xb,
              const bf16* __restrict__ Wqt, const bf16* __restrict__ Wkt,
              const bf16* __restrict__ Wvt,
              const float* __restrict__ bq, const float* __restrict__ bk,
              const float* __restrict__ bv,
              bf16* __restrict__ Q, bf16* __restrict__ K, bf16* __restrict__ Vt)
{
    __shared__ __align__(16) bf16 As[128 * 32];
    __shared__ __align__(16) bf16 Bs[128 * 32];
    __shared__ __align__(16) bf16 Eb[4][16 * 72];   // per-wave epilogue bounce

    const int t = threadIdx.x;
    const int lane = t & 63, w = t >> 6;
    const int quad = lane >> 4, l16 = lane & 15;
    const int m0 = blockIdx.x * 128;
    const int n0 = blockIdx.y * 128;
    const int which = blockIdx.z;
    const bf16*  W    = which == 0 ? Wqt : which == 1 ? Wkt : Wvt;
    const float* bias = which == 0 ? bq  : which == 1 ? bk  : bv;
    const float scale = which == 0 ? QSCALE : 1.0f;

    const int rm = (w >> 1) * 64, cn = (w & 1) * 64;

    floatx4 acc[4][4];
#pragma unroll
    for (int i = 0; i < 4; ++i)
#pragma unroll
        for (int j = 0; j < 4; ++j) acc[i][j] = (floatx4){0.f, 0.f, 0.f, 0.f};

    const int srow = t >> 2, sseg = (t & 3) * 8;
    const bf16* gA = xb + (size_t)(m0 + srow) * TD + sseg;
    const bf16* gB = W + (size_t)(n0 + srow) * TD + sseg;

    for (int kk = 0; kk < TD; kk += 32) {
        gl_lds16(gA + kk, As + t * 8);
        gl_lds16(gA + kk + (size_t)64 * TD, As + (t + 256) * 8);
        gl_lds16(gB + kk, Bs + t * 8);
        gl_lds16(gB + kk + (size_t)64 * TD, Bs + (t + 256) * 8);
        __syncthreads();
        bf16x8 af[4], bfr[4];
#pragma unroll
        for (int mb = 0; mb < 4; ++mb)
            af[mb] = *(const bf16x8*)&As[(rm + mb * 16 + l16) * 32 + quad * 8];
#pragma unroll
        for (int nb = 0; nb < 4; ++nb)
            bfr[nb] = *(const bf16x8*)&Bs[(cn + nb * 16 + l16) * 32 + quad * 8];
#pragma unroll
        for (int mb = 0; mb < 4; ++mb)
#pragma unroll
            for (int nb = 0; nb < 4; ++nb)
                acc[mb][nb] = MFMA16(af[mb], bfr[nb], acc[mb][nb]);
        __syncthreads();
    }

    float bsc[4];
#pragma unroll
    for (int nb = 0; nb < 4; ++nb)
        bsc[nb] = bias[n0 + cn + nb * 16 + l16] * scale;

    const int token0 = m0 + rm;
    const int b  = token0 >> 11;
    const int l0 = token0 & (TL - 1);
    const int h  = (n0 + cn) >> 6;
    const int bh = b * NH + h;
    bf16* Ew = Eb[w];

    if (which < 2) {
        bf16* gp = (which == 0 ? Q : K) + ((size_t)bh * TL + l0) * HD;
#pragma unroll
        for (int mb = 0; mb < 4; ++mb) {
#pragma unroll
            for (int nb = 0; nb < 4; ++nb)
#pragma unroll
                for (int r = 0; r < 4; ++r)
                    Ew[(quad * 4 + r) * 72 + nb * 16 + l16] =
                        (bf16)(acc[mb][nb][r] * scale + bsc[nb]);
#pragma unroll
            for (int i = 0; i < 2; ++i) {
                int row = i * 8 + (lane >> 3), seg = lane & 7;
                bf16x8 v = *(const bf16x8*)&Ew[row * 72 + seg * 8];
                *(bf16x8*)(gp + (size_t)(mb * 16 + row) * HD + seg * 8) = v;
            }
        }
    } else {
#pragma unroll
        for (int nb = 0; nb < 4; ++nb) {
#pragma unroll
            for (int mb = 0; mb < 4; ++mb) {
                bf16x4 pk;
#pragma unroll
                for (int r = 0; r < 4; ++r) pk[r] = (bf16)(acc[mb][nb][r] + bsc[nb]);
                *(bf16x4*)&Ew[l16 * 72 + mb * 16 + quad * 4] = pk;
            }
#pragma unroll
            for (int i = 0; i < 2; ++i) {
                int row = i * 8 + (lane >> 3), seg = lane & 7;
                bf16x8 v = *(const bf16x8*)&Ew[row * 72 + seg * 8];
                *(bf16x8*)(Vt + ((size_t)bh * HD + nb * 16 + row) * TL + l0 + seg * 8) = v;
            }
        }
    }
}

// ---------------------------------------------------------------------------
// MFMA flash attention v4: P never touches LDS.
// QK^T computed transposed (A=K, B=Q) with keys permuted across MFMA m-rows
// (kperm at staging) so the exp2'd C-registers re-pack directly into the PV
// A-fragment. LDS traffic per wave-step: 16 frag reads + 4 staging writes.
// ---------------------------------------------------------------------------
__global__ __launch_bounds__(256)
void attn_kernel(const bf16* __restrict__ Q, const bf16* __restrict__ K,
                 const bf16* __restrict__ Vt, bf16* __restrict__ O)
{
    __shared__ __align__(16) bf16 Ks[64 * 72];   // [kperm(key)][d], stride 72
    __shared__ __align__(16) bf16 Vs[64 * 72];   // [d][key], stride 72

    const int t = threadIdx.x;
    const int lane = t & 63, w = t >> 6;
    const int quad = lane >> 4, l16 = lane & 15;

    // XCD-aware swizzle: blocks on the same XCD (n%8) share one bh's K/V
    const int n = blockIdx.y * gridDim.x + blockIdx.x;   // 0..767
    const int xcd = n & 7, s = n >> 3;                   // s: 0..95
    const int bh = xcd * 6 + (s >> 4);
    const int q0 = (s & 15) * 128;

    const bf16* Qb = Q + (size_t)bh * TL * HD;
    const bf16* Kb = K + (size_t)bh * TL * HD;
    const bf16* Vb = Vt + (size_t)bh * HD * TL;

    const int qw = q0 + w * 32;
    bf16x8 qf[2][2];
#pragma unroll
    for (int mb = 0; mb < 2; ++mb)
#pragma unroll
        for (int ks = 0; ks < 2; ++ks)
            qf[mb][ks] = *(const bf16x8*)(Qb + (size_t)(qw + mb * 16 + l16) * HD
                                          + ks * 32 + quad * 8);

    float lrow[2] = {0.f, 0.f};      // per-lane partial row-sum for q = mb*16+l16
    floatx4 o[2][4];
#pragma unroll
    for (int mb = 0; mb < 2; ++mb)
#pragma unroll
        for (int db = 0; db < 4; ++db) o[mb][db] = (floatx4){0.f, 0.f, 0.f, 0.f};

    const int sr = t >> 3, ss = (t & 7) * 8;
    const int lr0 = kperm(sr), lr1 = kperm(sr + 32);

    for (int kt = 0; kt < TL / 64; ++kt) {
        const int k0 = kt * 64;
        __syncthreads();
        // stage K (rows permuted) and V
        *(float4*)&Ks[lr0 * 72 + ss] = *(const float4*)(Kb + (size_t)(k0 + sr) * HD + ss);
        *(float4*)&Ks[lr1 * 72 + ss] = *(const float4*)(Kb + (size_t)(k0 + sr + 32) * HD + ss);
        *(float4*)&Vs[sr * 72 + ss]  = *(const float4*)(Vb + (size_t)sr * TL + k0 + ss);
        *(float4*)&Vs[(sr + 32) * 72 + ss] = *(const float4*)(Vb + (size_t)(sr + 32) * TL + k0 + ss);
        __syncthreads();

        // S^T = K' Q^T : lane holds S[q=mb*16+l16][key=32(nb>>1)+4(nb&1)+8quad+r]
        floatx4 s2[2][4];
#pragma unroll
        for (int nb = 0; nb < 4; ++nb) {
            bf16x8 kf0 = *(const bf16x8*)&Ks[(nb * 16 + l16) * 72 + quad * 8];
            bf16x8 kf1 = *(const bf16x8*)&Ks[(nb * 16 + l16) * 72 + 32 + quad * 8];
#pragma unroll
            for (int mb = 0; mb < 2; ++mb) {
                floatx4 a = (floatx4){0.f, 0.f, 0.f, 0.f};
                a = MFMA16(kf0, qf[mb][0], a);
                a = MFMA16(kf1, qf[mb][1], a);
                s2[mb][nb] = a;
            }
        }

        // P = 2^S in-register; repack into PV A-fragments (keys ks*32+8quad+j)
        bf16x8 pA[2][2];
#pragma unroll
        for (int mb = 0; mb < 2; ++mb) {
#pragma unroll
            for (int ks = 0; ks < 2; ++ks) {
                floatx4 p0 = exp2x4(s2[mb][2 * ks]);
                floatx4 p1 = exp2x4(s2[mb][2 * ks + 1]);
                lrow[mb] += (p0.x + p0.y + p0.z + p0.w) + (p1.x + p1.y + p1.z + p1.w);
                bf16x8 pk;
                pk[0] = (bf16)p0.x; pk[1] = (bf16)p0.y; pk[2] = (bf16)p0.z; pk[3] = (bf16)p0.w;
                pk[4] = (bf16)p1.x; pk[5] = (bf16)p1.y; pk[6] = (bf16)p1.z; pk[7] = (bf16)p1.w;
                pA[mb][ks] = pk;
            }
        }

        // O += P V
#pragma unroll
        for (int ks = 0; ks < 2; ++ks) {
#pragma unroll
            for (int db = 0; db < 4; ++db) {
                bf16x8 vf = *(const bf16x8*)&Vs[(db * 16 + l16) * 72 + ks * 32 + quad * 8];
#pragma unroll
                for (int mb = 0; mb < 2; ++mb)
                    o[mb][db] = MFMA16(pA[mb][ks], vf, o[mb][db]);
            }
        }
    }

    // epilogue: complete row-sums (reduce over the 4 quads), normalize, store.
    const int b = bh / NH, h = bh % NH;
#pragma unroll
    for (int mb = 0; mb < 2; ++mb) {
        lrow[mb] += __shfl_xor(lrow[mb], 16);
        lrow[mb] += __shfl_xor(lrow[mb], 32);   // now lane holds sum for q=mb*16+l16
        floatx4 inv;
#pragma unroll
        for (int r = 0; r < 4; ++r)
            inv[r] = 1.0f / __shfl(lrow[mb], (lane & 48) | (quad * 4 + r));
#pragma unroll
        for (int db = 0; db < 4; ++db)
#pragma unroll
            for (int r = 0; r < 4; ++r) {
                int l = qw + mb * 16 + quad * 4 + r;
                O[((size_t)b * TL + l) * TD + h * HD + db * 16 + l16] =
                    (bf16)(o[mb][db][r] * inv[r]);
            }
    }
}

// ---------------------------------------------------------------------------
// Output projection: out fp32 = O_bf16 @ Wo + bo, LDS-bounce epilogue.
// ---------------------------------------------------------------------------
__global__ __launch_bounds__(256)
void oproj_gemm(const bf16* __restrict__ A, const bf16* __restrict__ Wt,
                const float* __restrict__ bo, float* __restrict__ out)
{
    __shared__ __align__(16) bf16 As[128 * 32];
    __shared__ __align__(16) bf16 Bs[128 * 32];
    __shared__ __align__(16) float Ef[4][16 * 68];   // per-wave f32 bounce

    const int t = threadIdx.x;
    const int lane = t & 63, w = t >> 6;
    const int quad = lane >> 4, l16 = lane & 15;
    const int m0 = blockIdx.x * 128;
    const int n0 = blockIdx.y * 128;
    const int rm = (w >> 1) * 64, cn = (w & 1) * 64;

    floatx4 acc[4][4];
#pragma unroll
    for (int i = 0; i < 4; ++i)
#pragma unroll
        for (int j = 0; j < 4; ++j) acc[i][j] = (floatx4){0.f, 0.f, 0.f, 0.f};

    const int srow = t >> 2, sseg = (t & 3) * 8;
    const bf16* gA = A + (size_t)(m0 + srow) * TD + sseg;
    const bf16* gB = Wt + (size_t)(n0 + srow) * TD + sseg;

    for (int kk = 0; kk < TD; kk += 32) {
        gl_lds16(gA + kk, As + t * 8);
        gl_lds16(gA + kk + (size_t)64 * TD, As + (t + 256) * 8);
        gl_lds16(gB + kk, Bs + t * 8);
        gl_lds16(gB + kk + (size_t)64 * TD, Bs + (t + 256) * 8);
        __syncthreads();
        bf16x8 af[4], bfr[4];
#pragma unroll
        for (int mb = 0; mb < 4; ++mb)
            af[mb] = *(const bf16x8*)&As[(rm + mb * 16 + l16) * 32 + quad * 8];
#pragma unroll
        for (int nb = 0; nb < 4; ++nb)
            bfr[nb] = *(const bf16x8*)&Bs[(cn + nb * 16 + l16) * 32 + quad * 8];
#pragma unroll
        for (int mb = 0; mb < 4; ++mb)
#pragma unroll
            for (int nb = 0; nb < 4; ++nb)
                acc[mb][nb] = MFMA16(af[mb], bfr[nb], acc[mb][nb]);
        __syncthreads();
    }

    float bb[4];
#pragma unroll
    for (int nb = 0; nb < 4; ++nb) bb[nb] = bo[n0 + cn + nb * 16 + l16];

    float* Ew = Ef[w];
#pragma unroll
    for (int mb = 0; mb < 4; ++mb) {
#pragma unroll
        for (int nb = 0; nb < 4; ++nb)
#pragma unroll
            for (int r = 0; r < 4; ++r)
                Ew[(quad * 4 + r) * 68 + nb * 16 + l16] = acc[mb][nb][r] + bb[nb];
#pragma unroll
        for (int i = 0; i < 4; ++i) {
            int row = i * 4 + (lane >> 4), seg = lane & 15;
            float4 v = *(const float4*)&Ew[row * 68 + seg * 4];
            *(float4*)(out + (size_t)(m0 + rm + mb * 16 + row) * TD + n0 + cn + seg * 4) = v;
        }
    }
}

// ---------------------------------------------------------------------------
extern "C" void kernel_launch(void* const* d_in, const int* in_sizes, int n_in,
                              void* d_out, int out_size, void* d_ws, size_t ws_size,
                              hipStream_t stream)
{
    const float* x  = (const float*)d_in[0];
    const float* Wq = (const float*)d_in[1];
    const float* bq = (const float*)d_in[2];
    const float* Wk = (const float*)d_in[3];
    const float* bk = (const float*)d_in[4];
    const float* Wv = (const float*)d_in[5];
    const float* bv = (const float*)d_in[6];
    const float* Wo = (const float*)d_in[7];
    const float* bo = (const float*)d_in[8];

    const size_t NXE = (size_t)MTOT * TD;    // 6,291,456
    const size_t NWE = (size_t)TD * TD;      // 589,824

    bf16* xb  = (bf16*)d_ws;
    bf16* Wqt = xb + NXE;
    bf16* Wkt = Wqt + NWE;
    bf16* Wvt = Wkt + NWE;
    bf16* Wot = Wvt + NWE;
    bf16* Qb  = Wot + NWE;
    bf16* Kb  = Qb + NXE;
    bf16* Vtb = Kb + NXE;
    bf16* Ob  = Vtb + NXE;

    cast_x_kernel<<<6144, 256, 0, stream>>>(x, xb);
    transw_kernel<<<dim3(12, 12, 4), 256, 0, stream>>>(Wq, Wk, Wv, Wo,
                                                       Wqt, Wkt, Wvt, Wot);
    qkv_gemm<<<dim3(MTOT / 128, TD / 128, 3), 256, 0, stream>>>(
        xb, Wqt, Wkt, Wvt, bq, bk, bv, Qb, Kb, Vtb);
    attn_kernel<<<dim3(TL / 128, NB * NH), 256, 0, stream>>>(Qb, Kb, Vtb, Ob);
    oproj_gemm<<<dim3(MTOT / 128, TD / 128), 256, 0, stream>>>(Ob, Wot, bo,
                                                               (float*)d_out);
}

// Round 5
// 215.818 us; speedup vs baseline: 7.0756x; 1.0127x over previous
//
#include <hip/hip_runtime.h>
#include <math.h>

#define TL 2048
#define TD 768
#define NH 12
#define HD 64
#define NB 4
#define MTOT (NB * TL)   // 8192

typedef __bf16 bf16;
typedef __attribute__((ext_vector_type(4))) __bf16 bf16x4;
typedef __attribute__((ext_vector_type(8))) __bf16 bf16x8;
typedef __attribute__((ext_vector_type(4))) float floatx4;

// Q pre-scale: 1/sqrt(64) * log2(e)  (softmax computed in exp2 domain)
#define QSCALE 0.18033688011112042f

#define MFMA16(A, B, C) __builtin_amdgcn_mfma_f32_16x16x32_bf16(A, B, C, 0, 0, 0)

__device__ __forceinline__ void gl_lds16(const void* g, void* l) {
    __builtin_amdgcn_global_load_lds(
        (const __attribute__((address_space(1))) void*)g,
        (__attribute__((address_space(3))) void*)l, 16, 0, 0);
}

__device__ __forceinline__ floatx4 exp2x4(floatx4 a) {
    floatx4 r;
    r.x = __builtin_amdgcn_exp2f(a.x);
    r.y = __builtin_amdgcn_exp2f(a.y);
    r.z = __builtin_amdgcn_exp2f(a.z);
    r.w = __builtin_amdgcn_exp2f(a.w);
    return r;
}

// Inverse of the key->LDS-row permutation that makes QK^T's C-registers
// coincide with PV's A-fragment layout. Row r holds key kperm_inv(r).
//   row bits [k5 k2 k4 k3 k1 k0] -> key
__device__ __forceinline__ int kperm_inv(int r) {
    return (r & 35) | (((r >> 2) & 3) << 3) | (((r >> 4) & 1) << 2);
}

// ---------------------------------------------------------------------------
// x fp32 -> bf16
// ---------------------------------------------------------------------------
__global__ __launch_bounds__(256)
void cast_x_kernel(const float* __restrict__ x, bf16* __restrict__ xb)
{
    size_t i = ((size_t)blockIdx.x * 256 + threadIdx.x) * 4;
    float4 v = *(const float4*)(x + i);
    bf16x4 o;
    o[0] = (bf16)v.x; o[1] = (bf16)v.y; o[2] = (bf16)v.z; o[3] = (bf16)v.w;
    *(bf16x4*)(xb + i) = o;
}

// ---------------------------------------------------------------------------
// W [768,768] fp32 -> W^T bf16
// ---------------------------------------------------------------------------
__global__ __launch_bounds__(256)
void transw_kernel(const float* __restrict__ W0, const float* __restrict__ W1,
                   const float* __restrict__ W2, const float* __restrict__ W3,
                   bf16* __restrict__ T0, bf16* __restrict__ T1,
                   bf16* __restrict__ T2, bf16* __restrict__ T3)
{
    const int z = blockIdx.z;
    const float* W = z == 0 ? W0 : z == 1 ? W1 : z == 2 ? W2 : W3;
    bf16*       T = z == 0 ? T0 : z == 1 ? T1 : z == 2 ? T2 : T3;
    __shared__ float Ts[64][65];
    const int t = threadIdx.x;
    const int k0 = blockIdx.x * 64, n0 = blockIdx.y * 64;
    const int rr = t >> 4, cc = (t & 15) * 4;
#pragma unroll
    for (int i = 0; i < 4; ++i) {
        int row = rr + i * 16;
        float4 v = *(const float4*)(W + (size_t)(k0 + row) * TD + n0 + cc);
        Ts[row][cc] = v.x; Ts[row][cc + 1] = v.y;
        Ts[row][cc + 2] = v.z; Ts[row][cc + 3] = v.w;
    }
    __syncthreads();
#pragma unroll
    for (int i = 0; i < 4; ++i) {
        int n = rr + i * 16;
        bf16x4 pk;
#pragma unroll
        for (int j = 0; j < 4; ++j) pk[j] = (bf16)Ts[cc + j][n];
        *(bf16x4*)(T + (size_t)(n0 + n) * TD + k0 + cc) = pk;
    }
}

// ---------------------------------------------------------------------------
// QKV GEMM: 128x128 tile, BK=64 (12 K-iters), XOR-swizzled LDS (no pad),
// global_load_lds staging, LDS-bounce coalesced epilogue.
// Q,K -> [bh][l][64] bf16 (Q pre-scaled by QSCALE); V -> [bh][d][2048] bf16.
// ---------------------------------------------------------------------------
__global__ __launch_bounds__(256)
void qkv_gemm(const bf16* __restrict__ xb,
              const bf16* __restrict__ Wqt, const bf16* __restrict__ Wkt,
              const bf16* __restrict__ Wvt,
              const float* __restrict__ bq, const float* __restrict__ bk,
              const float* __restrict__ bv,
              bf16* __restrict__ Q, bf16* __restrict__ K, bf16* __restrict__ Vt)
{
    __shared__ __align__(16) bf16 As[128 * 64];     // [row][seg^(row&7)]
    __shared__ __align__(16) bf16 Bs[128 * 64];
    __shared__ __align__(16) bf16 Eb[4][16 * 72];   // per-wave epilogue bounce

    const int t = threadIdx.x;
    const int lane = t & 63, w = t >> 6;
    const int quad = lane >> 4, l16 = lane & 15;
    const int m0 = blockIdx.x * 128;
    const int n0 = blockIdx.y * 128;
    const int which = blockIdx.z;
    const bf16*  W    = which == 0 ? Wqt : which == 1 ? Wkt : Wvt;
    const float* bias = which == 0 ? bq  : which == 1 ? bk  : bv;
    const float scale = which == 0 ? QSCALE : 1.0f;

    const int rm = (w >> 1) * 64, cn = (w & 1) * 64;

    floatx4 acc[4][4];
#pragma unroll
    for (int i = 0; i < 4; ++i)
#pragma unroll
        for (int j = 0; j < 4; ++j) acc[i][j] = (floatx4){0.f, 0.f, 0.f, 0.f};

    // staging sources: slot n = t + i*256; row = n>>3; seg = (n&7)^(row&7)
    const bf16* gA[4];
    const bf16* gB[4];
#pragma unroll
    for (int i = 0; i < 4; ++i) {
        int n = t + i * 256, r = n >> 3, s = ((n & 7) ^ (r & 7)) * 8;
        gA[i] = xb + (size_t)(m0 + r) * TD + s;
        gB[i] = W + (size_t)(n0 + r) * TD + s;
    }

    for (int kk = 0; kk < TD; kk += 64) {
#pragma unroll
        for (int i = 0; i < 4; ++i) {
            gl_lds16(gA[i] + kk, As + t * 8 + i * 2048);
            gl_lds16(gB[i] + kk, Bs + t * 8 + i * 2048);
        }
        __syncthreads();
#pragma unroll
        for (int ks = 0; ks < 2; ++ks) {
            bf16x8 af[4], bfr[4];
#pragma unroll
            for (int mb = 0; mb < 4; ++mb) {
                int r = rm + mb * 16 + l16;
                af[mb] = *(const bf16x8*)&As[r * 64 + (((ks * 4 + quad) ^ (r & 7)) * 8)];
            }
#pragma unroll
            for (int nb = 0; nb < 4; ++nb) {
                int r = cn + nb * 16 + l16;
                bfr[nb] = *(const bf16x8*)&Bs[r * 64 + (((ks * 4 + quad) ^ (r & 7)) * 8)];
            }
#pragma unroll
            for (int mb = 0; mb < 4; ++mb)
#pragma unroll
                for (int nb = 0; nb < 4; ++nb)
                    acc[mb][nb] = MFMA16(af[mb], bfr[nb], acc[mb][nb]);
        }
        __syncthreads();
    }

    float bsc[4];
#pragma unroll
    for (int nb = 0; nb < 4; ++nb)
        bsc[nb] = bias[n0 + cn + nb * 16 + l16] * scale;

    const int token0 = m0 + rm;
    const int b  = token0 >> 11;
    const int l0 = token0 & (TL - 1);
    const int h  = (n0 + cn) >> 6;
    const int bh = b * NH + h;
    bf16* Ew = Eb[w];

    if (which < 2) {
        bf16* gp = (which == 0 ? Q : K) + ((size_t)bh * TL + l0) * HD;
#pragma unroll
        for (int mb = 0; mb < 4; ++mb) {
#pragma unroll
            for (int nb = 0; nb < 4; ++nb)
#pragma unroll
                for (int r = 0; r < 4; ++r)
                    Ew[(quad * 4 + r) * 72 + nb * 16 + l16] =
                        (bf16)(acc[mb][nb][r] * scale + bsc[nb]);
#pragma unroll
            for (int i = 0; i < 2; ++i) {
                int row = i * 8 + (lane >> 3), seg = lane & 7;
                bf16x8 v = *(const bf16x8*)&Ew[row * 72 + seg * 8];
                *(bf16x8*)(gp + (size_t)(mb * 16 + row) * HD + seg * 8) = v;
            }
        }
    } else {
#pragma unroll
        for (int nb = 0; nb < 4; ++nb) {
#pragma unroll
            for (int mb = 0; mb < 4; ++mb) {
                bf16x4 pk;
#pragma unroll
                for (int r = 0; r < 4; ++r) pk[r] = (bf16)(acc[mb][nb][r] + bsc[nb]);
                *(bf16x4*)&Ew[l16 * 72 + mb * 16 + quad * 4] = pk;
            }
#pragma unroll
            for (int i = 0; i < 2; ++i) {
                int row = i * 8 + (lane >> 3), seg = lane & 7;
                bf16x8 v = *(const bf16x8*)&Ew[row * 72 + seg * 8];
                *(bf16x8*)(Vt + ((size_t)bh * HD + nb * 16 + row) * TL + l0 + seg * 8) = v;
            }
        }
    }
}

// ---------------------------------------------------------------------------
// MFMA flash attention v5: P never touches LDS; K/V staged via
// global_load_lds with the key permutation folded into the per-lane global
// source address and XOR segment swizzle instead of padding.
// ---------------------------------------------------------------------------
__global__ __launch_bounds__(256)
void attn_kernel(const bf16* __restrict__ Q, const bf16* __restrict__ K,
                 const bf16* __restrict__ Vt, bf16* __restrict__ O)
{
    __shared__ __align__(16) bf16 Ks[64 * 64];   // [kperm(key)][seg^(row&7)]
    __shared__ __align__(16) bf16 Vs[64 * 64];   // [d][seg^(d&7)] over keys

    const int t = threadIdx.x;
    const int lane = t & 63, w = t >> 6;
    const int quad = lane >> 4, l16 = lane & 15;

    // XCD-aware swizzle: blocks on the same XCD (n%8) share one bh's K/V
    const int n = blockIdx.y * gridDim.x + blockIdx.x;   // 0..767
    const int xcd = n & 7, s = n >> 3;                   // s: 0..95
    const int bh = xcd * 6 + (s >> 4);
    const int q0 = (s & 15) * 128;

    const bf16* Qb = Q + (size_t)bh * TL * HD;
    const bf16* Kb = K + (size_t)bh * TL * HD;
    const bf16* Vb = Vt + (size_t)bh * HD * TL;

    const int qw = q0 + w * 32;
    bf16x8 qf[2][2];
#pragma unroll
    for (int mb = 0; mb < 2; ++mb)
#pragma unroll
        for (int ks = 0; ks < 2; ++ks)
            qf[mb][ks] = *(const bf16x8*)(Qb + (size_t)(qw + mb * 16 + l16) * HD
                                          + ks * 32 + quad * 8);

    float lrow[2] = {0.f, 0.f};      // per-lane partial row-sum for q = mb*16+l16
    floatx4 o[2][4];
#pragma unroll
    for (int mb = 0; mb < 2; ++mb)
#pragma unroll
        for (int db = 0; db < 4; ++db) o[mb][db] = (floatx4){0.f, 0.f, 0.f, 0.f};

    // staging sources: slots n = t (i=0), t+256 (i=1); row = n>>3, 8 slots/row
    const bf16* gK[2];
    const bf16* gV[2];
#pragma unroll
    for (int i = 0; i < 2; ++i) {
        int nn = t + i * 256, r = nn >> 3, sg = ((nn & 7) ^ (r & 7)) * 8;
        gK[i] = Kb + (size_t)kperm_inv(r) * HD + sg;   // + k0*HD per step
        gV[i] = Vb + (size_t)r * TL + sg;              // + k0 per step
    }

    for (int kt = 0; kt < TL / 64; ++kt) {
        const int k0 = kt * 64;
        __syncthreads();
#pragma unroll
        for (int i = 0; i < 2; ++i) {
            gl_lds16(gK[i] + (size_t)k0 * HD, Ks + t * 8 + i * 2048);
            gl_lds16(gV[i] + k0,              Vs + t * 8 + i * 2048);
        }
        __syncthreads();

        // S^T = K' Q^T : lane holds S[q=mb*16+l16][key=32(nb>>1)+4(nb&1)+8quad+r]
        floatx4 s2[2][4];
#pragma unroll
        for (int nb = 0; nb < 4; ++nb) {
            int r = nb * 16 + l16;
            bf16x8 kf0 = *(const bf16x8*)&Ks[r * 64 + ((quad ^ (r & 7)) * 8)];
            bf16x8 kf1 = *(const bf16x8*)&Ks[r * 64 + (((4 + quad) ^ (r & 7)) * 8)];
#pragma unroll
            for (int mb = 0; mb < 2; ++mb) {
                floatx4 a = (floatx4){0.f, 0.f, 0.f, 0.f};
                a = MFMA16(kf0, qf[mb][0], a);
                a = MFMA16(kf1, qf[mb][1], a);
                s2[mb][nb] = a;
            }
        }

        // P = 2^S in-register; repack into PV A-fragments (keys ks*32+8quad+j)
        bf16x8 pA[2][2];
#pragma unroll
        for (int mb = 0; mb < 2; ++mb) {
#pragma unroll
            for (int ks = 0; ks < 2; ++ks) {
                floatx4 p0 = exp2x4(s2[mb][2 * ks]);
                floatx4 p1 = exp2x4(s2[mb][2 * ks + 1]);
                lrow[mb] += (p0.x + p0.y + p0.z + p0.w) + (p1.x + p1.y + p1.z + p1.w);
                bf16x8 pk;
                pk[0] = (bf16)p0.x; pk[1] = (bf16)p0.y; pk[2] = (bf16)p0.z; pk[3] = (bf16)p0.w;
                pk[4] = (bf16)p1.x; pk[5] = (bf16)p1.y; pk[6] = (bf16)p1.z; pk[7] = (bf16)p1.w;
                pA[mb][ks] = pk;
            }
        }

        // O += P V
#pragma unroll
        for (int ks = 0; ks < 2; ++ks) {
#pragma unroll
            for (int db = 0; db < 4; ++db) {
                int r = db * 16 + l16;
                bf16x8 vf = *(const bf16x8*)&Vs[r * 64 + (((ks * 4 + quad) ^ (r & 7)) * 8)];
#pragma unroll
                for (int mb = 0; mb < 2; ++mb)
                    o[mb][db] = MFMA16(pA[mb][ks], vf, o[mb][db]);
            }
        }
    }

    // epilogue: complete row-sums (reduce over the 4 quads), normalize, store.
    const int b = bh / NH, h = bh % NH;
#pragma unroll
    for (int mb = 0; mb < 2; ++mb) {
        lrow[mb] += __shfl_xor(lrow[mb], 16);
        lrow[mb] += __shfl_xor(lrow[mb], 32);   // now lane holds sum for q=mb*16+l16
        floatx4 inv;
#pragma unroll
        for (int r = 0; r < 4; ++r)
            inv[r] = 1.0f / __shfl(lrow[mb], (lane & 48) | (quad * 4 + r));
#pragma unroll
        for (int db = 0; db < 4; ++db)
#pragma unroll
            for (int r = 0; r < 4; ++r) {
                int l = qw + mb * 16 + quad * 4 + r;
                O[((size_t)b * TL + l) * TD + h * HD + db * 16 + l16] =
                    (bf16)(o[mb][db][r] * inv[r]);
            }
    }
}

// ---------------------------------------------------------------------------
// Output projection: out fp32 = O_bf16 @ Wo + bo. BK=64, XOR swizzle,
// LDS-bounce epilogue.
// ---------------------------------------------------------------------------
__global__ __launch_bounds__(256)
void oproj_gemm(const bf16* __restrict__ A, const bf16* __restrict__ Wt,
                const float* __restrict__ bo, float* __restrict__ out)
{
    __shared__ __align__(16) bf16 As[128 * 64];
    __shared__ __align__(16) bf16 Bs[128 * 64];
    __shared__ __align__(16) float Ef[4][16 * 68];   // per-wave f32 bounce

    const int t = threadIdx.x;
    const int lane = t & 63, w = t >> 6;
    const int quad = lane >> 4, l16 = lane & 15;
    const int m0 = blockIdx.x * 128;
    const int n0 = blockIdx.y * 128;
    const int rm = (w >> 1) * 64, cn = (w & 1) * 64;

    floatx4 acc[4][4];
#pragma unroll
    for (int i = 0; i < 4; ++i)
#pragma unroll
        for (int j = 0; j < 4; ++j) acc[i][j] = (floatx4){0.f, 0.f, 0.f, 0.f};

    const bf16* gA[4];
    const bf16* gB[4];
#pragma unroll
    for (int i = 0; i < 4; ++i) {
        int n = t + i * 256, r = n >> 3, s = ((n & 7) ^ (r & 7)) * 8;
        gA[i] = A + (size_t)(m0 + r) * TD + s;
        gB[i] = Wt + (size_t)(n0 + r) * TD + s;
    }

    for (int kk = 0; kk < TD; kk += 64) {
#pragma unroll
        for (int i = 0; i < 4; ++i) {
            gl_lds16(gA[i] + kk, As + t * 8 + i * 2048);
            gl_lds16(gB[i] + kk, Bs + t * 8 + i * 2048);
        }
        __syncthreads();
#pragma unroll
        for (int ks = 0; ks < 2; ++ks) {
            bf16x8 af[4], bfr[4];
#pragma unroll
            for (int mb = 0; mb < 4; ++mb) {
                int r = rm + mb * 16 + l16;
                af[mb] = *(const bf16x8*)&As[r * 64 + (((ks * 4 + quad) ^ (r & 7)) * 8)];
            }
#pragma unroll
            for (int nb = 0; nb < 4; ++nb) {
                int r = cn + nb * 16 + l16;
                bfr[nb] = *(const bf16x8*)&Bs[r * 64 + (((ks * 4 + quad) ^ (r & 7)) * 8)];
            }
#pragma unroll
            for (int mb = 0; mb < 4; ++mb)
#pragma unroll
                for (int nb = 0; nb < 4; ++nb)
                    acc[mb][nb] = MFMA16(af[mb], bfr[nb], acc[mb][nb]);
        }
        __syncthreads();
    }

    float bb[4];
#pragma unroll
    for (int nb = 0; nb < 4; ++nb) bb[nb] = bo[n0 + cn + nb * 16 + l16];

    float* Ew = Ef[w];
#pragma unroll
    for (int mb = 0; mb < 4; ++mb) {
#pragma unroll
        for (int nb = 0; nb < 4; ++nb)
#pragma unroll
            for (int r = 0; r < 4; ++r)
                Ew[(quad * 4 + r) * 68 + nb * 16 + l16] = acc[mb][nb][r] + bb[nb];
#pragma unroll
        for (int i = 0; i < 4; ++i) {
            int row = i * 4 + (lane >> 4), seg = lane & 15;
            float4 v = *(const float4*)&Ew[row * 68 + seg * 4];
            *(float4*)(out + (size_t)(m0 + rm + mb * 16 + row) * TD + n0 + cn + seg * 4) = v;
        }
    }
}

// ---------------------------------------------------------------------------
extern "C" void kernel_launch(void* const* d_in, const int* in_sizes, int n_in,
                              void* d_out, int out_size, void* d_ws, size_t ws_size,
                              hipStream_t stream)
{
    const float* x  = (const float*)d_in[0];
    const float* Wq = (const float*)d_in[1];
    const float* bq = (const float*)d_in[2];
    const float* Wk = (const float*)d_in[3];
    const float* bk = (const float*)d_in[4];
    const float* Wv = (const float*)d_in[5];
    const float* bv = (const float*)d_in[6];
    const float* Wo = (const float*)d_in[7];
    const float* bo = (const float*)d_in[8];

    const size_t NXE = (size_t)MTOT * TD;    // 6,291,456
    const size_t NWE = (size_t)TD * TD;      // 589,824

    bf16* xb  = (bf16*)d_ws;
    bf16* Wqt = xb + NXE;
    bf16* Wkt = Wqt + NWE;
    bf16* Wvt = Wkt + NWE;
    bf16* Wot = Wvt + NWE;
    bf16* Qb  = Wot + NWE;
    bf16* Kb  = Qb + NXE;
    bf16* Vtb = Kb + NXE;
    bf16* Ob  = Vtb + NXE;

    cast_x_kernel<<<6144, 256, 0, stream>>>(x, xb);
    transw_kernel<<<dim3(12, 12, 4), 256, 0, stream>>>(Wq, Wk, Wv, Wo,
                                                       Wqt, Wkt, Wvt, Wot);
    qkv_gemm<<<dim3(MTOT / 128, TD / 128, 3), 256, 0, stream>>>(
        xb, Wqt, Wkt, Wvt, bq, bk, bv, Qb, Kb, Vtb);
    attn_kernel<<<dim3(TL / 128, NB * NH), 256, 0, stream>>>(Qb, Kb, Vtb, Ob);
    oproj_gemm<<<dim3(MTOT / 128, TD / 128), 256, 0, stream>>>(Ob, Wot, bo,
                                                               (float*)d_out);
}